// Round 4
// baseline (148.343 us; speedup 1.0000x reference)
//
#include <hip/hip_runtime.h>

// DistNet: out[n] = sigmoid((min_p ||x_n - p||^2 + alpha) / beta)
// beta = softplus(beta_raw), alpha = -beta*ln(1000)
// x: [65536,128] f32, points: [2048,128] f32, beta_raw: [1] f32, out: [65536] f32
//
// R4 design: 128-thread blocks (2 waves) so each SIMD hosts waves from two
// DIFFERENT blocks (4 blocks/CU) -> one block's barrier drain overlaps the
// other's compute. LDS async double-buffered 64-pt stages as in R3. pnorm
// read from global (L1-hot) to keep LDS/block at 33 KB (4 blocks/CU).

#define NROWS 65536
#define NPTS  2048
#define DIMS  128
#define LOG1000F 6.9077542789816375f
#define STAGE_PTS 64
#define NSTAGES (NPTS / STAGE_PTS)   // 32

typedef __attribute__((ext_vector_type(8))) __bf16 bf16x8;
typedef __attribute__((ext_vector_type(8))) unsigned short ushort8;
typedef __attribute__((ext_vector_type(4))) float f32x4;

union BfCast { ushort8 u; bf16x8 b; };

__device__ inline unsigned short f2bf(float f) {
    unsigned int u = __float_as_uint(f);
    u += 0x7FFFu + ((u >> 16) & 1u);
    return (unsigned short)(u >> 16);
}

// --- pre-kernel: points f32 -> bf16 in ws, plus ||p||^2 ---------------------
__global__ __launch_bounds__(256) void prep_points_kernel(
    const float* __restrict__ pts, unsigned short* __restrict__ ptsbf,
    float* __restrict__ pnorm)
{
    int tid  = threadIdx.x;
    int lane = tid & 63;
    int w    = tid >> 6;
    int pt   = blockIdx.x * 4 + w;            // one wave per point
    const float2 v = *reinterpret_cast<const float2*>(
        pts + (size_t)pt * DIMS + lane * 2);  // 2 features per lane
    ushort2 b;
    b.x = f2bf(v.x);
    b.y = f2bf(v.y);
    *reinterpret_cast<ushort2*>(ptsbf + (size_t)pt * DIMS + lane * 2) = b;
    float ss = v.x * v.x + v.y * v.y;
    ss += __shfl_xor(ss, 1, 64);
    ss += __shfl_xor(ss, 2, 64);
    ss += __shfl_xor(ss, 4, 64);
    ss += __shfl_xor(ss, 8, 64);
    ss += __shfl_xor(ss, 16, 64);
    ss += __shfl_xor(ss, 32, 64);
    if (lane == 0) pnorm[pt] = ss;
}

// --- main kernel ------------------------------------------------------------
// grid: NROWS/64 = 1024 blocks x 128 threads (2 waves); wave owns 32 rows.
__global__ __launch_bounds__(128, 2) void distnet_main_kernel(
    const float* __restrict__ x, const unsigned short* __restrict__ ptsbf,
    const float* __restrict__ pnorm, const float* __restrict__ beta_raw,
    float* __restrict__ out)
{
    // B stage buffers, fragment order: [buf][(tile*4+chunk)*64 + lane] x 16B
    __shared__ ushort8 s_b[2][STAGE_PTS * DIMS / 8];   // 2 x 16 KB
    __shared__ float s_xn[64];                         // 2 waves x 32 rows

    int tid  = threadIdx.x;
    int wave = tid >> 6;
    int lane = tid & 63;
    int m    = lane & 15;          // A row / B col (point) index
    int q    = lane >> 4;          // k-quad
    int r0   = blockIdx.x * 64 + wave * 32;

    // A fragments: 2 row-tiles x 4 k-chunks; lane holds A[m][k=q*8+j].
    bf16x8 afrag[2][4];
#pragma unroll
    for (int t = 0; t < 2; ++t) {
        const float* xrow = x + (size_t)(r0 + t * 16 + m) * DIMS + q * 8;
        float sumsq = 0.f;
#pragma unroll
        for (int c = 0; c < 4; ++c) {
            float4 v0 = *reinterpret_cast<const float4*>(xrow + c * 32);
            float4 v1 = *reinterpret_cast<const float4*>(xrow + c * 32 + 4);
            BfCast cv;
            cv.u[0] = f2bf(v0.x); cv.u[1] = f2bf(v0.y);
            cv.u[2] = f2bf(v0.z); cv.u[3] = f2bf(v0.w);
            cv.u[4] = f2bf(v1.x); cv.u[5] = f2bf(v1.y);
            cv.u[6] = f2bf(v1.z); cv.u[7] = f2bf(v1.w);
            afrag[t][c] = cv.b;
            sumsq += v0.x * v0.x + v0.y * v0.y + v0.z * v0.z + v0.w * v0.w;
            sumsq += v1.x * v1.x + v1.y * v1.y + v1.z * v1.z + v1.w * v1.w;
        }
        sumsq += __shfl_xor(sumsq, 16, 64);
        sumsq += __shfl_xor(sumsq, 32, 64);
        if (lane < 16) s_xn[wave * 32 + t * 16 + lane] = sumsq;
    }

    // Async stage issue: wave w stages pt-tiles {2w, 2w+1} (8 x 1 KB loads).
    // Lane's global source: point p = s*64 + tt*16 + m, k-bytes = q*16 + c*64.
    // LDS dest: wave-uniform base &s_b[buf][(tt*4+c)*64], +lane*16 implicit.
    const unsigned char* gbase = (const unsigned char*)ptsbf;
    auto issue_stage = [&](int s, int buf) {
#pragma unroll
        for (int i = 0; i < 8; ++i) {
            int tt = wave * 2 + (i >> 2);
            int c  = i & 3;
            size_t pbyte = (size_t)(s * STAGE_PTS + tt * 16 + m) * (DIMS * 2)
                           + (size_t)q * 16 + (size_t)c * 64;
            const void* g = gbase + pbyte;
            void* l = (void*)&s_b[buf][(tt * 4 + c) * 64];
            __builtin_amdgcn_global_load_lds(
                (const __attribute__((address_space(1))) unsigned int*)g,
                (__attribute__((address_space(3))) unsigned int*)l,
                16, 0, 0);
        }
    };

    issue_stage(0, 0);

    // runmin tracks min_p (||p||^2 - 2 x.p); ||x||^2 + clip folded in at end.
    float runmin[2][4] = {{1e30f, 1e30f, 1e30f, 1e30f},
                          {1e30f, 1e30f, 1e30f, 1e30f}};

    for (int s = 0; s < NSTAGES; ++s) {
        __syncthreads();   // stage-s LDS writes visible; prev readers done
        if (s + 1 < NSTAGES) issue_stage(s + 1, (s + 1) & 1);

        const ushort8* bbuf = &s_b[s & 1][0];
#pragma unroll
        for (int t = 0; t < 4; ++t) {
            float pn = pnorm[s * STAGE_PTS + t * 16 + m];   // L1-hot, 64B seg
            ushort8 bfr[4];
#pragma unroll
            for (int c = 0; c < 4; ++c)
                bfr[c] = bbuf[(t * 4 + c) * 64 + lane];     // ds_read_b128
            f32x4 acc0 = {0.f, 0.f, 0.f, 0.f};
            f32x4 acc1 = {0.f, 0.f, 0.f, 0.f};
#pragma unroll
            for (int c = 0; c < 4; ++c) {
                BfCast cv; cv.u = bfr[c];
                acc0 = __builtin_amdgcn_mfma_f32_16x16x32_bf16(afrag[0][c], cv.b, acc0, 0, 0, 0);
                acc1 = __builtin_amdgcn_mfma_f32_16x16x32_bf16(afrag[1][c], cv.b, acc1, 0, 0, 0);
            }
#pragma unroll
            for (int r = 0; r < 4; ++r) {
                runmin[0][r] = fminf(runmin[0][r], fmaf(-2.f, acc0[r], pn));
                runmin[1][r] = fminf(runmin[1][r], fmaf(-2.f, acc1[r], pn));
            }
        }
    }

    // C/D layout: col = m, row_local = q*4 + r. Reduce min over the 16 cols.
    float br    = beta_raw[0];
    float beta  = log1pf(expf(br));
    float alpha = -beta * LOG1000F;
#pragma unroll
    for (int t = 0; t < 2; ++t) {
#pragma unroll
        for (int r = 0; r < 4; ++r) {
            float v = runmin[t][r];
            v = fminf(v, __shfl_xor(v, 1, 64));
            v = fminf(v, __shfl_xor(v, 2, 64));
            v = fminf(v, __shfl_xor(v, 4, 64));
            v = fminf(v, __shfl_xor(v, 8, 64));
            if (m == 0) {
                float xnv = s_xn[wave * 32 + t * 16 + q * 4 + r];
                float d2  = fmaxf(xnv + v, 0.f);
                float z   = (d2 + alpha) / beta;
                out[r0 + t * 16 + q * 4 + r] = 1.f / (1.f + expf(-z));
            }
        }
    }
}

extern "C" void kernel_launch(void* const* d_in, const int* in_sizes, int n_in,
                              void* d_out, int out_size, void* d_ws, size_t ws_size,
                              hipStream_t stream) {
    const float* x        = (const float*)d_in[0];
    const float* pts      = (const float*)d_in[1];
    const float* beta_raw = (const float*)d_in[2];
    float* out            = (float*)d_out;

    unsigned short* ptsbf = (unsigned short*)d_ws;                  // 512 KB
    float* pnorm = (float*)((char*)d_ws + (size_t)NPTS * DIMS * 2); // 8 KB

    prep_points_kernel<<<NPTS / 4, 256, 0, stream>>>(pts, ptsbf, pnorm);
    distnet_main_kernel<<<NROWS / 64, 128, 0, stream>>>(x, ptsbf, pnorm,
                                                        beta_raw, out);
}

// Round 5
// 103.998 us; speedup vs baseline: 1.4264x; 1.4264x over previous
//
#include <hip/hip_runtime.h>

// DistNet: out[n] = sigmoid((min_p ||x_n - p||^2 + alpha) / beta)
// beta = softplus(beta_raw), alpha = -beta*ln(1000)
// x: [65536,128] f32, points: [2048,128] f32, beta_raw: [1] f32, out: [65536] f32
//
// R5 design: cross-term in fp8 e4m3 via mfma_scale_f32_16x16x128_f8f6f4
// (scales=1.0): K=128 in ONE MFMA, 2x rate, half the B bytes. R3 block
// structure (256 thr / 4 waves / 32 rows/wave / 512 blocks = 2 per CU),
// double-buffered global_load_lds staging of 128-pt stages (16 KB).
// Dot products are k-permutation invariant, so A/B fragment k-order only
// needs to be mutually consistent; C/D layout is the verified 16x16 one.

#define NROWS 65536
#define NPTS  2048
#define DIMS  128
#define LOG1000F 6.9077542789816375f
#define STAGE_PTS 128
#define NSTAGES (NPTS / STAGE_PTS)   // 16

typedef __attribute__((ext_vector_type(8))) int i32x8;
typedef __attribute__((ext_vector_type(4))) float f32x4;

union AFrag { int d[8]; i32x8 v; };
union BFrag { uint4 u4[2]; i32x8 v; };

// --- pre-kernel: points f32 -> fp8 e4m3 in ws, plus ||p||^2 -----------------
__global__ __launch_bounds__(256) void prep_points_kernel(
    const float* __restrict__ pts, unsigned char* __restrict__ ptsf8,
    float* __restrict__ pnorm)
{
    int tid  = threadIdx.x;
    int lane = tid & 63;
    int w    = tid >> 6;
    int pt   = blockIdx.x * 4 + w;            // one wave per point
    const float2 v = *reinterpret_cast<const float2*>(
        pts + (size_t)pt * DIMS + lane * 2);  // 2 features per lane
    int pk = __builtin_amdgcn_cvt_pk_fp8_f32(v.x, v.y, 0, false);
    *reinterpret_cast<unsigned short*>(ptsf8 + (size_t)pt * DIMS + lane * 2) =
        (unsigned short)(pk & 0xFFFF);
    float ss = v.x * v.x + v.y * v.y;
    ss += __shfl_xor(ss, 1, 64);
    ss += __shfl_xor(ss, 2, 64);
    ss += __shfl_xor(ss, 4, 64);
    ss += __shfl_xor(ss, 8, 64);
    ss += __shfl_xor(ss, 16, 64);
    ss += __shfl_xor(ss, 32, 64);
    if (lane == 0) pnorm[pt] = ss;
}

// --- main kernel ------------------------------------------------------------
// grid: NROWS/128 = 512 blocks x 256 threads (4 waves); wave owns 32 rows.
__global__ __launch_bounds__(256, 2) void distnet_main_kernel(
    const float* __restrict__ x, const unsigned char* __restrict__ ptsf8,
    const float* __restrict__ pnorm, const float* __restrict__ beta_raw,
    float* __restrict__ out)
{
    // stage: 128 pts x 128 B = 16 KB = 1024 x 16B units, fragment order:
    // unit[(tile*2 + half)*64 + lane], tile=pt-tile (16 pts), half=k 0..15/16..31
    __shared__ uint4 s_b[2][STAGE_PTS * DIMS / 16];   // 2 x 16 KB
    __shared__ float s_xn[128];

    int tid  = threadIdx.x;
    int wave = tid >> 6;
    int lane = tid & 63;
    int m    = lane & 15;          // A row / B col (point) index
    int q    = lane >> 4;          // k-quad: lane covers k = q*32 .. q*32+31
    int r0   = blockIdx.x * 128 + wave * 32;

    // A fragments: 2 row-tiles; lane holds A[m][k=q*32+j], j=0..31 (32 B).
    AFrag afrag[2];
#pragma unroll
    for (int t = 0; t < 2; ++t) {
        const float* xp = x + (size_t)(r0 + t * 16 + m) * DIMS + q * 32;
        float ss = 0.f;
#pragma unroll
        for (int d = 0; d < 8; ++d) {
            float4 v = *reinterpret_cast<const float4*>(xp + d * 4);
            int w0 = __builtin_amdgcn_cvt_pk_fp8_f32(v.x, v.y, 0, false);
            w0 = __builtin_amdgcn_cvt_pk_fp8_f32(v.z, v.w, w0, true);
            afrag[t].d[d] = w0;
            ss += v.x * v.x + v.y * v.y + v.z * v.z + v.w * v.w;
        }
        ss += __shfl_xor(ss, 16, 64);
        ss += __shfl_xor(ss, 32, 64);
        if (lane < 16) s_xn[wave * 32 + t * 16 + lane] = ss;
    }

    // Async staging: 8 pt-tiles/stage; wave w stages tiles {2w, 2w+1},
    // halves c=0,1. Lane src: p = s*128 + tt*16 + m, bytes p*128+q*32+c*16.
    // LDS dst: wave-uniform &s_b[buf][(tt*2+c)*64] (+lane*16 implicit).
    const unsigned char* gbase = ptsf8;
    auto issue_stage = [&](int s, int buf) {
#pragma unroll
        for (int i = 0; i < 4; ++i) {
            int tt = wave * 2 + (i >> 1);
            int c  = i & 1;
            size_t pbyte = (size_t)(s * STAGE_PTS + tt * 16 + m) * DIMS
                           + (size_t)q * 32 + (size_t)c * 16;
            const void* g = gbase + pbyte;
            void* l = (void*)&s_b[buf][(tt * 2 + c) * 64];
            __builtin_amdgcn_global_load_lds(
                (const __attribute__((address_space(1))) unsigned int*)g,
                (__attribute__((address_space(3))) unsigned int*)l,
                16, 0, 0);
        }
    };

    issue_stage(0, 0);

    // runmin tracks min_p (||p||^2 - 2 x.p); ||x||^2 + clip folded in at end.
    float runmin[2][4] = {{1e30f, 1e30f, 1e30f, 1e30f},
                          {1e30f, 1e30f, 1e30f, 1e30f}};

    for (int s = 0; s < NSTAGES; ++s) {
        __syncthreads();   // stage-s LDS writes visible; prev readers done
        if (s + 1 < NSTAGES) issue_stage(s + 1, (s + 1) & 1);

        const uint4* bbuf = &s_b[s & 1][0];
#pragma unroll
        for (int t = 0; t < 8; ++t) {
            BFrag bf;
            bf.u4[0] = bbuf[(t * 2 + 0) * 64 + lane];   // ds_read_b128
            bf.u4[1] = bbuf[(t * 2 + 1) * 64 + lane];
            float pn = pnorm[s * STAGE_PTS + t * 16 + m]; // L1-hot
            f32x4 acc0 = {0.f, 0.f, 0.f, 0.f};
            f32x4 acc1 = {0.f, 0.f, 0.f, 0.f};
            acc0 = __builtin_amdgcn_mfma_scale_f32_16x16x128_f8f6f4(
                afrag[0].v, bf.v, acc0, 0, 0, 0, 0x7F7F7F7F, 0, 0x7F7F7F7F);
            acc1 = __builtin_amdgcn_mfma_scale_f32_16x16x128_f8f6f4(
                afrag[1].v, bf.v, acc1, 0, 0, 0, 0x7F7F7F7F, 0, 0x7F7F7F7F);
#pragma unroll
            for (int r = 0; r < 4; ++r) {
                runmin[0][r] = fminf(runmin[0][r], fmaf(-2.f, acc0[r], pn));
                runmin[1][r] = fminf(runmin[1][r], fmaf(-2.f, acc1[r], pn));
            }
        }
    }

    // C/D layout: col = m, row_local = q*4 + r. Reduce min over the 16 cols.
    float br    = beta_raw[0];
    float beta  = log1pf(expf(br));
    float alpha = -beta * LOG1000F;
#pragma unroll
    for (int t = 0; t < 2; ++t) {
#pragma unroll
        for (int r = 0; r < 4; ++r) {
            float v = runmin[t][r];
            v = fminf(v, __shfl_xor(v, 1, 64));
            v = fminf(v, __shfl_xor(v, 2, 64));
            v = fminf(v, __shfl_xor(v, 4, 64));
            v = fminf(v, __shfl_xor(v, 8, 64));
            if (m == 0) {
                float xnv = s_xn[wave * 32 + t * 16 + q * 4 + r];
                float d2  = fmaxf(xnv + v, 0.f);
                float z   = (d2 + alpha) / beta;
                out[r0 + t * 16 + q * 4 + r] = 1.f / (1.f + expf(-z));
            }
        }
    }
}

extern "C" void kernel_launch(void* const* d_in, const int* in_sizes, int n_in,
                              void* d_out, int out_size, void* d_ws, size_t ws_size,
                              hipStream_t stream) {
    const float* x        = (const float*)d_in[0];
    const float* pts      = (const float*)d_in[1];
    const float* beta_raw = (const float*)d_in[2];
    float* out            = (float*)d_out;

    unsigned char* ptsf8 = (unsigned char*)d_ws;                    // 256 KB
    float* pnorm = (float*)((char*)d_ws + (size_t)NPTS * DIMS);     // 8 KB

    prep_points_kernel<<<NPTS / 4, 256, 0, stream>>>(pts, ptsf8, pnorm);
    distnet_main_kernel<<<NROWS / 128, 256, 0, stream>>>(x, ptsf8, pnorm,
                                                         beta_raw, out);
}

// Round 6
// 99.032 us; speedup vs baseline: 1.4979x; 1.0501x over previous
//
#include <hip/hip_runtime.h>

// DistNet: out[n] = sigmoid((min_p ||x_n - p||^2 + alpha) / beta)
// beta = softplus(beta_raw), alpha = -beta*ln(1000)
// x: [65536,128] f32, points: [2048,128] f32, beta_raw: [1] f32, out: [65536] f32
//
// R6 design: fp8 e4m3 mfma_scale_f32_16x16x128 (K=128, one MFMA per tile),
// 256-pt double-buffered global_load_lds stages (8 stages, fewer barriers),
// ||p||^2 restored to LDS (R5's in-loop global pnorm loads doubled the
// per-stage stall; ds_read_b32 pipelines under lgkmcnt instead).
// 256-thr blocks / 4 waves / 32 rows per wave / 512 blocks = 2 per CU.

#define NROWS 65536
#define NPTS  2048
#define DIMS  128
#define LOG1000F 6.9077542789816375f
#define STAGE_PTS 256
#define NSTAGES (NPTS / STAGE_PTS)   // 8

typedef __attribute__((ext_vector_type(8))) int i32x8;
typedef __attribute__((ext_vector_type(4))) float f32x4;

union AFrag { int d[8]; i32x8 v; };
union BFrag { uint4 u4[2]; i32x8 v; };

// --- pre-kernel: points f32 -> fp8 e4m3 in ws, plus ||p||^2 -----------------
__global__ __launch_bounds__(256) void prep_points_kernel(
    const float* __restrict__ pts, unsigned char* __restrict__ ptsf8,
    float* __restrict__ pnorm)
{
    int tid  = threadIdx.x;
    int lane = tid & 63;
    int w    = tid >> 6;
    int pt   = blockIdx.x * 4 + w;            // one wave per point
    const float2 v = *reinterpret_cast<const float2*>(
        pts + (size_t)pt * DIMS + lane * 2);  // 2 features per lane
    int pk = __builtin_amdgcn_cvt_pk_fp8_f32(v.x, v.y, 0, false);
    *reinterpret_cast<unsigned short*>(ptsf8 + (size_t)pt * DIMS + lane * 2) =
        (unsigned short)(pk & 0xFFFF);
    float ss = v.x * v.x + v.y * v.y;
    ss += __shfl_xor(ss, 1, 64);
    ss += __shfl_xor(ss, 2, 64);
    ss += __shfl_xor(ss, 4, 64);
    ss += __shfl_xor(ss, 8, 64);
    ss += __shfl_xor(ss, 16, 64);
    ss += __shfl_xor(ss, 32, 64);
    if (lane == 0) pnorm[pt] = ss;
}

// --- main kernel ------------------------------------------------------------
// grid: NROWS/128 = 512 blocks x 256 threads (4 waves); wave owns 32 rows.
__global__ __launch_bounds__(256, 2) void distnet_main_kernel(
    const float* __restrict__ x, const unsigned char* __restrict__ ptsf8,
    const float* __restrict__ pnorm, const float* __restrict__ beta_raw,
    float* __restrict__ out)
{
    // stage: 256 pts x 128 B = 32 KB = 2048 x 16B units, fragment order:
    // unit[(tile*2 + half)*64 + lane]; tile = 16-pt tile, half = k-halves.
    __shared__ uint4 s_b[2][STAGE_PTS * DIMS / 16];   // 2 x 32 KB
    __shared__ float s_pn[NPTS];                      // 8 KB
    __shared__ float s_xn[128];

    int tid  = threadIdx.x;
    for (int i = tid; i < NPTS / 4; i += 256)
        *reinterpret_cast<float4*>(&s_pn[i * 4]) =
            reinterpret_cast<const float4*>(pnorm)[i];

    int wave = tid >> 6;
    int lane = tid & 63;
    int m    = lane & 15;          // A row / B col (point) index
    int q    = lane >> 4;          // k-quad: lane covers k = q*32 .. q*32+31
    int r0   = blockIdx.x * 128 + wave * 32;

    // A fragments: 2 row-tiles; lane holds A[m][k=q*32+j], j=0..31 (32 B).
    AFrag afrag[2];
#pragma unroll
    for (int t = 0; t < 2; ++t) {
        const float* xp = x + (size_t)(r0 + t * 16 + m) * DIMS + q * 32;
        float ss = 0.f;
#pragma unroll
        for (int d = 0; d < 8; ++d) {
            float4 v = *reinterpret_cast<const float4*>(xp + d * 4);
            int w0 = __builtin_amdgcn_cvt_pk_fp8_f32(v.x, v.y, 0, false);
            w0 = __builtin_amdgcn_cvt_pk_fp8_f32(v.z, v.w, w0, true);
            afrag[t].d[d] = w0;
            ss += v.x * v.x + v.y * v.y + v.z * v.z + v.w * v.w;
        }
        ss += __shfl_xor(ss, 16, 64);
        ss += __shfl_xor(ss, 32, 64);
        if (lane < 16) s_xn[wave * 32 + t * 16 + lane] = ss;
    }

    // Async staging: 16 pt-tiles/stage; wave w stages tiles {4w..4w+3},
    // halves c=0,1 -> 8 x 1KB loads. Lane src: p = s*256 + tt*16 + m,
    // byte = p*128 + q*32 + c*16. LDS dst: uniform &s_b[buf][(tt*2+c)*64].
    const unsigned char* gbase = ptsf8;
    auto issue_stage = [&](int s, int buf) {
#pragma unroll
        for (int i = 0; i < 8; ++i) {
            int tt = wave * 4 + (i >> 1);
            int c  = i & 1;
            size_t pbyte = (size_t)(s * STAGE_PTS + tt * 16 + m) * DIMS
                           + (size_t)q * 32 + (size_t)c * 16;
            const void* g = gbase + pbyte;
            void* l = (void*)&s_b[buf][(tt * 2 + c) * 64];
            __builtin_amdgcn_global_load_lds(
                (const __attribute__((address_space(1))) unsigned int*)g,
                (__attribute__((address_space(3))) unsigned int*)l,
                16, 0, 0);
        }
    };

    issue_stage(0, 0);

    // runmin tracks min_p (||p||^2 - 2 x.p); ||x||^2 + clip folded in at end.
    float runmin[2][4] = {{1e30f, 1e30f, 1e30f, 1e30f},
                          {1e30f, 1e30f, 1e30f, 1e30f}};

    for (int s = 0; s < NSTAGES; ++s) {
        __syncthreads();   // stage-s LDS writes visible; prev readers done
        if (s + 1 < NSTAGES) issue_stage(s + 1, (s + 1) & 1);

        const uint4* bbuf = &s_b[s & 1][0];
#pragma unroll
        for (int t = 0; t < 16; ++t) {
            BFrag bf;
            bf.u4[0] = bbuf[(t * 2 + 0) * 64 + lane];   // ds_read_b128
            bf.u4[1] = bbuf[(t * 2 + 1) * 64 + lane];
            float pn = s_pn[s * STAGE_PTS + t * 16 + m]; // ds_read_b32
            f32x4 acc0 = {0.f, 0.f, 0.f, 0.f};
            f32x4 acc1 = {0.f, 0.f, 0.f, 0.f};
            acc0 = __builtin_amdgcn_mfma_scale_f32_16x16x128_f8f6f4(
                afrag[0].v, bf.v, acc0, 0, 0, 0, 0x7F7F7F7F, 0, 0x7F7F7F7F);
            acc1 = __builtin_amdgcn_mfma_scale_f32_16x16x128_f8f6f4(
                afrag[1].v, bf.v, acc1, 0, 0, 0, 0x7F7F7F7F, 0, 0x7F7F7F7F);
#pragma unroll
            for (int r = 0; r < 4; ++r) {
                runmin[0][r] = fminf(runmin[0][r], fmaf(-2.f, acc0[r], pn));
                runmin[1][r] = fminf(runmin[1][r], fmaf(-2.f, acc1[r], pn));
            }
        }
    }

    // C/D layout: col = m, row_local = q*4 + r. Reduce min over the 16 cols.
    float br    = beta_raw[0];
    float beta  = log1pf(expf(br));
    float alpha = -beta * LOG1000F;
#pragma unroll
    for (int t = 0; t < 2; ++t) {
#pragma unroll
        for (int r = 0; r < 4; ++r) {
            float v = runmin[t][r];
            v = fminf(v, __shfl_xor(v, 1, 64));
            v = fminf(v, __shfl_xor(v, 2, 64));
            v = fminf(v, __shfl_xor(v, 4, 64));
            v = fminf(v, __shfl_xor(v, 8, 64));
            if (m == 0) {
                float xnv = s_xn[wave * 32 + t * 16 + q * 4 + r];
                float d2  = fmaxf(xnv + v, 0.f);
                float z   = (d2 + alpha) / beta;
                out[r0 + t * 16 + q * 4 + r] = 1.f / (1.f + expf(-z));
            }
        }
    }
}

extern "C" void kernel_launch(void* const* d_in, const int* in_sizes, int n_in,
                              void* d_out, int out_size, void* d_ws, size_t ws_size,
                              hipStream_t stream) {
    const float* x        = (const float*)d_in[0];
    const float* pts      = (const float*)d_in[1];
    const float* beta_raw = (const float*)d_in[2];
    float* out            = (float*)d_out;

    unsigned char* ptsf8 = (unsigned char*)d_ws;                    // 256 KB
    float* pnorm = (float*)((char*)d_ws + (size_t)NPTS * DIMS);     // 8 KB

    prep_points_kernel<<<NPTS / 4, 256, 0, stream>>>(pts, ptsf8, pnorm);
    distnet_main_kernel<<<NROWS / 128, 256, 0, stream>>>(x, ptsf8, pnorm,
                                                         beta_raw, out);
}